// Round 16
// baseline (449.762 us; speedup 1.0000x reference)
//
#include <hip/hip_runtime.h>
#include <stdint.h>

#define T_STEPS 100
#define BATCH   256
#define NIN     784
#define NHID    512
#define NOUT    10

// ===========================================================================
// NUMERICS CONTRACT (validated PASS R5-R23):
//   * gemm1: per C element, fp32 single-accumulator fmaf chain, k ascending,
//     panel folds cur1 = ((P1+P2)+P3)+b1 via single __fadd_rn each. BIT-EXACT.
//   * gemm2: f64 accumulation of fp32 products (s in {0.0f,1.0f}), +b2 in
//     f64, single f32 rounding. R24 order: lane chains over h =
//     {4l..4l+3, 256+4l..256+4l+3} ascending -> 16-partial l-ascending
//     group sums -> 4 g-ascending adds. Deterministic; reassociation-only
//     delta vs R20/R22 (class validated: absmax stayed 0.0625 across R20/21).
//   * recurrences: fp32 _rn ops, ((0.95*mem + cur) - rst), no contraction;
//     spike/reset = (mem > 1.0f). VERBATIM.
// PERF JOURNAL:
//   * R9/R13/R17 -> REGISTER-CLIFF LAW: gemm1 frozen (acc[8][8], BK=8,
//     1 float4/matrix staging, untouched epilogue; VGPR 56; ~264us floor).
//   * R12 542.8 -> R14 495 -> R15 483 -> R16 469 -> R18 452.6 -> R19 444.2
//     -> R20 437.0 BEST. R21 454.6 REGRESSION (f64 shfl butterfly: 6x LDS
//     pipe ops). R22 445.2 (pad+lgkm = noise). R23 447.2 NEUTRAL (float4
//     producers): leaky NOT issue-bound -> modeled ~50us.
//   * ACCOUNTING (R23): gemm1 264 + leaky ~50 + g2lout ~12 = ~326 vs 447
//     measured -> ~100us in launch gaps + spk1 round-trip (52.4 MB re-read).
//   * R24: fuse leaky+gemm2+lout into ONE kernel (3->2 launches). Spikes
//     cross waves as __ballot bitmasks (1 KB LDS); producer waves do the
//     gemm2 dot one phase later from LDS W2 (linear, contiguous float4,
//     conflict-free; W2-in-regs would break the 128-VGPR/16-wave limit).
//     R22 reduction scheme. Deletes g2lout launch+gap + spk1 re-read.
//     Pre-registered: fail/regress -> revert; neutral -> plateau is
//     harness-level.
// ===========================================================================

// ---------------------------------------------------------------------------
// GEMM1 dual-panel kernel — DO NOT MODIFY (register-cliff law, R9/R13/R17).
// ---------------------------------------------------------------------------
#define BM 128
#define BN 128
#define BK 8
#define PANEL_K 384

__global__ __launch_bounds__(256) void gemm1_dual(
    const float* __restrict__ X, const float* __restrict__ W,
    float* __restrict__ C1, float* __restrict__ C2)
{
    __shared__ float As[2][BK][BM + 4];   // 2 x 4224 B
    __shared__ float Bs[2][BK][BN + 4];   // 2 x 4224 B

    const int tid = threadIdx.x;
    const int bm  = blockIdx.x * BM;
    const int bn  = blockIdx.y * BN;
    const int kb  = blockIdx.z ? PANEL_K : 0;
    float* __restrict__ C = blockIdx.z ? C2 : C1;

    const int row  = tid >> 1;           // 0..127
    const int koff = (tid & 1) * 4;      // 0 or 4

    const int w    = tid >> 6;
    const int lane = tid & 63;
    const int tm   = (w & 1) * 64 + (lane & 7) * 8;    // 0..120
    const int tn   = (w >> 1) * 64 + (lane >> 3) * 8;  // 0..120

    float acc[8][8];
    #pragma unroll
    for (int i = 0; i < 8; ++i)
        #pragma unroll
        for (int j = 0; j < 8; ++j) acc[i][j] = 0.f;

    const float* Xp = X + (size_t)(bm + row) * NIN + kb + koff;
    const float* Wp = W + (size_t)(bn + row) * NIN + kb + koff;

    float4 pa = *(const float4*)(Xp);
    float4 pb = *(const float4*)(Wp);
    As[0][koff+0][row] = pa.x; As[0][koff+1][row] = pa.y;
    As[0][koff+2][row] = pa.z; As[0][koff+3][row] = pa.w;
    Bs[0][koff+0][row] = pb.x; Bs[0][koff+1][row] = pb.y;
    Bs[0][koff+2][row] = pb.z; Bs[0][koff+3][row] = pb.w;

    const int NITER = PANEL_K / BK;   // 48
    for (int it = 0; it < NITER; ++it) {
        const int cur = it & 1;
        __syncthreads();

        if (it + 1 < NITER) {
            const int k0 = (it + 1) * BK;
            pa = *(const float4*)(Xp + k0);
            pb = *(const float4*)(Wp + k0);
        }

        #pragma unroll
        for (int kk = 0; kk < BK; ++kk) {   // k ascending
            float4 av0 = *(const float4*)&As[cur][kk][tm];
            float4 av1 = *(const float4*)&As[cur][kk][tm + 4];
            float4 bv0 = *(const float4*)&Bs[cur][kk][tn];
            float4 bv1 = *(const float4*)&Bs[cur][kk][tn + 4];
            float a[8] = {av0.x, av0.y, av0.z, av0.w, av1.x, av1.y, av1.z, av1.w};
            float b[8] = {bv0.x, bv0.y, bv0.z, bv0.w, bv1.x, bv1.y, bv1.z, bv1.w};
            #pragma unroll
            for (int i = 0; i < 8; ++i)
                #pragma unroll
                for (int j = 0; j < 8; ++j)
                    acc[i][j] = fmaf(a[i], b[j], acc[i][j]);
        }

        if (it + 1 < NITER) {
            const int nxt = cur ^ 1;
            As[nxt][koff+0][row] = pa.x; As[nxt][koff+1][row] = pa.y;
            As[nxt][koff+2][row] = pa.z; As[nxt][koff+3][row] = pa.w;
            Bs[nxt][koff+0][row] = pb.x; Bs[nxt][koff+1][row] = pb.y;
            Bs[nxt][koff+2][row] = pb.z; Bs[nxt][koff+3][row] = pb.w;
        }
    }

    #pragma unroll
    for (int i = 0; i < 8; ++i) {
        size_t r = (size_t)(bm + tm + i) * NHID + bn + tn;
        *(float4*)&C[r]     = make_float4(acc[i][0], acc[i][1], acc[i][2], acc[i][3]);
        *(float4*)&C[r + 4] = make_float4(acc[i][4], acc[i][5], acc[i][6], acc[i][7]);
    }
}

// ---------------------------------------------------------------------------
// Fused hidden-Leaky + tail-fold + GEMM2 + output-Leaky (R24).
// 256 blocks x 1024 threads; block bb owns batch row bb end-to-end.
//   Phase c (c = 0..13, barrier-separated):
//     consumers (tid<512, c<=12): chunk c — verbatim leaky chains; spike
//       bits published per wave via __ballot into spkb[c&1].
//     producers (tid>=512): (a) c<12: float4-load P1/P2 chunk c+1 into
//       LDS FIFO parity (c+1)&1; (b) c>=1: gemm2 for chunk c-1 — wave pw
//       handles t = 8(c-1)+pw: reconstruct s from spkb[(c-1)&1], f64 dot
//       with LDS W2 (linear, lane reads contiguous float4 pairs at
//       4l / 256+4l — conflict-free), R22 ps/ps2 reduction, cur2 + c2s.
//   After loop: threads 0..9 run VERBATIM output recurrence from c2s.
// LDS ~143 KB (<160): xs4 6.4 + FIFOs 64 + spkb 1 + w2 20 + ps 45 +
// ps2 2.8 + c2s 4. Aliasing safety (ws-fallback c2==spk_out) unchanged:
// reads t>=8(c+1) vs writes t<=8c+7, barrier-ordered, disjoint columns.
// ---------------------------------------------------------------------------
__global__ __launch_bounds__(1024) void leaky_g2_fused(
    float* __restrict__ mem_io,        // P1 on entry, mem1 on exit
    const float* c2p,                  // P2 partial (d_ws; may alias spk_out)
    float* spk_out,
    const float* __restrict__ X,
    const float* __restrict__ W1,
    const float* __restrict__ b1,
    const float* __restrict__ W2,
    const float* __restrict__ b2,
    float* __restrict__ cur2,
    float* __restrict__ spk2,
    float* __restrict__ mem2)
{
    __shared__ float4 xs4[T_STEPS][4];           // 6.4 KB
    __shared__ float  p1s[2][8][NHID];           // 32 KB
    __shared__ float  p2s[2][8][NHID];           // 32 KB
    __shared__ unsigned long long spkb[2][8][8]; // 1 KB: spike bitmasks
    __shared__ float  w2sl[NOUT * NHID];         // 20 KB, linear
    __shared__ double ps [8][64][11];            // 45 KB (2-way-free stride)
    __shared__ double ps2[8][4][11];             // 2.8 KB
    __shared__ float  c2s[T_STEPS][NOUT];        // 4 KB
    __shared__ float  b2s[NOUT];

    const int tid = threadIdx.x;
    const int bb  = blockIdx.x;                  // batch row
    const size_t STRIDE = (size_t)BATCH * NHID;
    const size_t base   = (size_t)bb * NHID;

    // stage X tail (threads 0..399)
    if (tid < T_STEPS * 4) {
        const int t = tid >> 2, q = tid & 3;
        xs4[t][q] = *(const float4*)(X + (size_t)t * BATCH * NIN
                                       + (size_t)bb * NIN + 768 + q * 4);
    }
    // stage W2 linear (all threads) + b2
    for (int i = tid; i < NOUT * NHID; i += 1024) w2sl[i] = W2[i];
    if (tid < NOUT) b2s[tid] = b2[tid];

    const bool producer = (tid >= 512);
    const int  lane     = tid & 511;             // consumer col 0..511
    const size_t col    = base + lane;

    float wt[16];
    float bias = 0.f;
    float mem  = 0.f;

    if (producer) {
        // prologue: chunk 0 (t = 0..7) into buf 0, float4 (v6 pattern)
        const int p = tid - 512;
        const int s = p >> 8;                    // 0: P1, 1: P2
        const int q = p & 255;
        const float* src = s ? c2p : mem_io;
        float4 v[4];
        #pragma unroll
        for (int jj = 0; jj < 4; ++jj) {
            const int flat = q + 256 * jj;
            const int j = flat >> 7, f4 = flat & 127;
            v[jj] = *(const float4*)(src + base + 4 * f4 + (size_t)j * STRIDE);
        }
        #pragma unroll
        for (int jj = 0; jj < 4; ++jj) {
            const int flat = q + 256 * jj;
            const int j = flat >> 7, f4 = flat & 127;
            float* dst = s ? &p2s[0][j][4 * f4] : &p1s[0][j][4 * f4];
            *(float4*)dst = v[jj];
        }
    } else {
        const int h = lane;
        const float* wp = W1 + (size_t)h * NIN + 768;
        float4 w0  = *(const float4*)(wp);
        float4 w1v = *(const float4*)(wp + 4);
        float4 w2v = *(const float4*)(wp + 8);
        float4 w3v = *(const float4*)(wp + 12);
        wt[0]=w0.x;  wt[1]=w0.y;  wt[2]=w0.z;  wt[3]=w0.w;
        wt[4]=w1v.x; wt[5]=w1v.y; wt[6]=w1v.z; wt[7]=w1v.w;
        wt[8]=w2v.x; wt[9]=w2v.y; wt[10]=w2v.z; wt[11]=w2v.w;
        wt[12]=w3v.x; wt[13]=w3v.y; wt[14]=w3v.z; wt[15]=w3v.w;
        bias = b1[h];
    }

    __syncthreads();   // xs4 + W2 + chunk 0 ready

    // phases: c = 0..13. Chunk c covers t = 8c..8c+nt-1 (nt=4 for c=12).
    for (int c = 0; c <= 13; ++c) {
        if (producer) {
            const int p  = tid - 512;
            const int pw = p >> 6;               // producer wave 0..7
            const int pl = p & 63;               // lane in wave

            // (a) load chunk c+1
            if (c < 12) {
                const int t0n = (c + 1) * 8;
                const int nb  = (c + 1 == 12) ? 4 : 8;
                const int nIt = nb >> 1;
                const int s = p >> 8;
                const int q = p & 255;
                const float* src = s ? c2p : mem_io;
                const int pbuf = (c + 1) & 1;
                float4 v[4];
                #pragma unroll
                for (int jj = 0; jj < 4; ++jj) {
                    if (jj < nIt) {
                        const int flat = q + 256 * jj;
                        const int j = flat >> 7, f4 = flat & 127;
                        v[jj] = *(const float4*)(src + base + 4 * f4
                                                 + (size_t)(t0n + j) * STRIDE);
                    }
                }
                #pragma unroll
                for (int jj = 0; jj < 4; ++jj) {
                    if (jj < nIt) {
                        const int flat = q + 256 * jj;
                        const int j = flat >> 7, f4 = flat & 127;
                        float* dst = s ? &p2s[pbuf][j][4 * f4]
                                       : &p1s[pbuf][j][4 * f4];
                        *(float4*)dst = v[jj];
                    }
                }
            }

            // (b) gemm2 for chunk c-1
            if (c >= 1) {
                const int cp  = c - 1;
                const int ntp = (cp == 12) ? 4 : 8;
                if (pw < ntp) {
                    const int t   = cp * 8 + pw;
                    const int cb2 = cp & 1;
                    // spike bits: h = 4*pl..4*pl+3 from word pl>>4,
                    //             h = 256+4*pl..+3 from word 4+(pl>>4)
                    const unsigned long long mA = spkb[cb2][pw][pl >> 4];
                    const unsigned long long mB = spkb[cb2][pw][4 + (pl >> 4)];
                    const int sh = (4 * pl) & 63;
                    float sv[8];
                    #pragma unroll
                    for (int j = 0; j < 4; ++j) {
                        sv[j]     = ((mA >> (sh + j)) & 1ull) ? 1.0f : 0.0f;
                        sv[4 + j] = ((mB >> (sh + j)) & 1ull) ? 1.0f : 0.0f;
                    }
                    // per-o chains, h ascending {4l..4l+3, 256+4l..+3}
                    #pragma unroll
                    for (int o = 0; o < NOUT; ++o) {
                        float4 wA = *(const float4*)&w2sl[o * NHID + 4 * pl];
                        float4 wB = *(const float4*)&w2sl[o * NHID + 256 + 4 * pl];
                        double d = 0.0;
                        d = fma((double)sv[0], (double)wA.x, d);
                        d = fma((double)sv[1], (double)wA.y, d);
                        d = fma((double)sv[2], (double)wA.z, d);
                        d = fma((double)sv[3], (double)wA.w, d);
                        d = fma((double)sv[4], (double)wB.x, d);
                        d = fma((double)sv[5], (double)wB.y, d);
                        d = fma((double)sv[6], (double)wB.z, d);
                        d = fma((double)sv[7], (double)wB.w, d);
                        ps[pw][pl][o] = d;
                    }
                    asm volatile("s_waitcnt lgkmcnt(0)" ::: "memory");
                    if (pl < 40) {
                        const int o = pl >> 2, g = pl & 3;
                        double d = 0.0;
                        #pragma unroll
                        for (int l2 = 0; l2 < 16; ++l2)
                            d += ps[pw][g * 16 + l2][o];
                        ps2[pw][g][o] = d;
                    }
                    asm volatile("s_waitcnt lgkmcnt(0)" ::: "memory");
                    if (pl < 10) {
                        const int o = pl;
                        double d = ((ps2[pw][0][o] + ps2[pw][1][o])
                                    + ps2[pw][2][o]) + ps2[pw][3][o];
                        const float cv = (float)(d + (double)b2s[o]);
                        cur2[(size_t)t * (BATCH * NOUT)
                             + (size_t)bb * NOUT + o] = cv;
                        c2s[t][o] = cv;
                    }
                }
            }
        } else if (c <= 12) {
            const int nt = (c == 12) ? 4 : 8;
            const int cb = c & 1;
            const int cw = tid >> 6;             // consumer wave 0..7
            #pragma unroll
            for (int j = 0; j < 8; ++j) {
                if (j < nt) {
                    const int t = c * 8 + j;
                    const float p1 = p1s[cb][j][lane];
                    const float p2 = p2s[cb][j][lane];
                    float4 v0 = xs4[t][0], v1 = xs4[t][1];
                    float4 v2 = xs4[t][2], v3 = xs4[t][3];
                    // acc3: 16-k ascending single-accumulator fmaf chain
                    float a = 0.f;
                    a = fmaf(v0.x, wt[0], a);  a = fmaf(v0.y, wt[1], a);
                    a = fmaf(v0.z, wt[2], a);  a = fmaf(v0.w, wt[3], a);
                    a = fmaf(v1.x, wt[4], a);  a = fmaf(v1.y, wt[5], a);
                    a = fmaf(v1.z, wt[6], a);  a = fmaf(v1.w, wt[7], a);
                    a = fmaf(v2.x, wt[8], a);  a = fmaf(v2.y, wt[9], a);
                    a = fmaf(v2.z, wt[10], a); a = fmaf(v2.w, wt[11], a);
                    a = fmaf(v3.x, wt[12], a); a = fmaf(v3.y, wt[13], a);
                    a = fmaf(v3.z, wt[14], a); a = fmaf(v3.w, wt[15], a);

                    const float cur = __fadd_rn(__fadd_rn(__fadd_rn(p1, p2), a), bias);
                    const float rst = (mem > 1.0f) ? 1.0f : 0.0f;
                    mem = __fsub_rn(__fadd_rn(__fmul_rn(0.95f, mem), cur), rst);

                    const bool sp = (mem > 1.0f);
                    const size_t off = col + (size_t)t * STRIDE;
                    spk_out[off] = sp ? 1.0f : 0.0f;
                    mem_io[off]  = mem;

                    const unsigned long long msk = __ballot(sp);
                    if ((tid & 63) == 0) spkb[cb][j][cw] = msk;
                }
            }
        }
        __syncthreads();
    }

    // output Leaky recurrence: VERBATIM fp32 _rn chain, threads 0..9
    if (tid < NOUT) {
        const int o = tid;
        float m2 = 0.f;
        for (int t = 0; t < T_STEPS; ++t) {
            const float cur = c2s[t][o];
            const float rst = (m2 > 1.0f) ? 1.0f : 0.0f;
            m2 = __fsub_rn(__fadd_rn(__fmul_rn(0.95f, m2), cur), rst);
            const size_t off = (size_t)t * (BATCH * NOUT) + (size_t)bb * NOUT + o;
            spk2[off] = (m2 > 1.0f) ? 1.0f : 0.0f;
            mem2[off] = m2;
        }
    }
}

// ---------------------------------------------------------------------------
extern "C" void kernel_launch(void* const* d_in, const int* in_sizes, int n_in,
                              void* d_out, int out_size, void* d_ws, size_t ws_size,
                              hipStream_t stream) {
    const float* x  = (const float*)d_in[0];   // (100, 256, 784)
    const float* w1 = (const float*)d_in[1];   // (512, 784)
    const float* b1 = (const float*)d_in[2];   // (512,)
    const float* w2 = (const float*)d_in[3];   // (10, 512)
    const float* b2 = (const float*)d_in[4];   // (10,)

    float* out = (float*)d_out;
    // Output tuple order: (cur2, spk2, spk1, mem2, mem1), each stacked over T.
    float* cur2_out = out;                       // 256000
    float* spk2_out = out + 256000;              // 256000
    float* spk1_out = out + 512000;              // 13107200
    float* mem2_out = out + 13619200;            // 256000
    float* mem1_out = out + 13875200;            // 13107200

    const int M = T_STEPS * BATCH;               // 25600

    // P2 scratch: prefer d_ws; fallback = spk1 region (chunk-disjoint,
    // barrier-ordered aliasing) only if ws too small.
    const size_t p2_bytes = (size_t)M * NHID * sizeof(float);   // 52.4 MB
    float* p2buf = (d_ws != nullptr && ws_size >= p2_bytes)
                       ? (float*)d_ws : spk1_out;

    // 1) P1 -> mem1 region, P2 -> p2buf, one z=2 launch.
    dim3 gp(M / BM, NHID / BN, 2);               // (200, 4, 2) = 1600 blocks
    gemm1_dual<<<gp, 256, 0, stream>>>(x, w1, mem1_out, p2buf);

    // 2) fused: hidden Leaky + tail fold + GEMM2 + output Leaky.
    leaky_g2_fused<<<BATCH, 1024, 0, stream>>>(
        mem1_out, p2buf, spk1_out, x, w1, b1, w2, b2,
        cur2_out, spk2_out, mem2_out);
}